// Round 4
// baseline (341.785 us; speedup 1.0000x reference)
//
#include <hip/hip_runtime.h>
#include <math.h>

// SpectralTokenizer: 262144 rows x 100 fp32 -> per row 5 frames (hop 8, len 64),
// Hann window, rfft-64, log1p(|.|), freq-major flatten -> 165 fp32 per row.
//
// R6: kernel ~56us vs ~36-40us floor; R3's counters on this structure showed
// Occupancy 22.7% / VALUBusy 42% -> latency-bound, LDS-limited (42.2KB -> 3
// blocks/CU = 15 of 32 waves). Halve LDS: split the output transpose into two
// 32-row passes through a reused 21.1KB buffer (recon A -> barrier -> store A
// -> barrier -> recon B -> barrier -> store B). 6 blocks/CU = 30 waves.
// Compute structure (scattered float4 loads -> registers -> FFT) unchanged —
// that part is verified best. Unlike R3's regression: no extra LDS traffic,
// no bank conflicts, and the extra barriers are hidden by doubled occupancy.

#define ROWS_PER_BLOCK 64
#define BLOCK_THREADS (ROWS_PER_BLOCK * 5)   // 320 = 5 waves
#define HALF_ROWS 32
#define ROW_LEN 100
#define OUT_PER_ROW 165                      // 33 freq * 5 frames
#define CHUNK_F4 (HALF_ROWS * OUT_PER_ROW / 4)  // 1320 float4 per half

typedef float nfloat4 __attribute__((ext_vector_type(4)));  // native vec for nt-store

// cos/sin(2*pi*j/32), j=0..15  (FFT-32 twiddles, e^{-2pi i j/32} = c - i*s)
constexpr float W32C[16] = {
    1.0f, 0.980785280403230f, 0.923879532511287f, 0.831469612302545f,
    0.707106781186548f, 0.555570233019602f, 0.382683432365090f, 0.195090322016128f,
    0.0f, -0.195090322016128f, -0.382683432365090f, -0.555570233019602f,
    -0.707106781186548f, -0.831469612302545f, -0.923879532511287f, -0.980785280403230f};
constexpr float W32S[16] = {
    0.0f, 0.195090322016128f, 0.382683432365090f, 0.555570233019602f,
    0.707106781186548f, 0.831469612302545f, 0.923879532511287f, 0.980785280403230f,
    1.0f, 0.980785280403230f, 0.923879532511287f, 0.831469612302545f,
    0.707106781186548f, 0.555570233019602f, 0.382683432365090f, 0.195090322016128f};

// cos/sin(2*pi*k/64), k=0..32 (recon twiddles e^{-2pi i k/64} = TC - i*TS; also Hann table)
constexpr float TC[33] = {
    1.0f, 0.995184726672197f, 0.980785280403230f, 0.956940335732209f,
    0.923879532511287f, 0.881921264348355f, 0.831469612302545f, 0.773010453362737f,
    0.707106781186548f, 0.634393284163645f, 0.555570233019602f, 0.471396736825998f,
    0.382683432365090f, 0.290284677254462f, 0.195090322016128f, 0.098017140329561f,
    0.0f, -0.098017140329561f, -0.195090322016128f, -0.290284677254462f,
    -0.382683432365090f, -0.471396736825998f, -0.555570233019602f, -0.634393284163645f,
    -0.707106781186548f, -0.773010453362737f, -0.831469612302545f, -0.881921264348355f,
    -0.923879532511287f, -0.956940335732209f, -0.980785280403230f, -0.995184726672197f,
    -1.0f};
constexpr float TS[33] = {
    0.0f, 0.098017140329561f, 0.195090322016128f, 0.290284677254462f,
    0.382683432365090f, 0.471396736825998f, 0.555570233019602f, 0.634393284163645f,
    0.707106781186548f, 0.773010453362737f, 0.831469612302545f, 0.881921264348355f,
    0.923879532511287f, 0.956940335732209f, 0.980785280403230f, 0.995184726672197f,
    1.0f, 0.995184726672197f, 0.980785280403230f, 0.956940335732209f,
    0.923879532511287f, 0.881921264348355f, 0.831469612302545f, 0.773010453362737f,
    0.707106781186548f, 0.634393284163645f, 0.555570233019602f, 0.471396736825998f,
    0.382683432365090f, 0.290284677254462f, 0.195090322016128f, 0.098017140329561f};

// 5-bit bit reversal (involution)
constexpr int BR32[32] = {0, 16, 8, 24, 4, 20, 12, 28, 2, 18, 10, 26, 6, 22, 14, 30,
                          1, 17, 9, 25, 5, 21, 13, 29, 3, 19, 11, 27, 7, 23, 15, 31};

// periodic Hann scaled by 0.5 (the even/odd extraction factor folded in):
// w[n] = 0.25*(1 - cos(2*pi*n/64)); n compile-time -> folds to a literal
__device__ __forceinline__ constexpr float hann_half(int n) {
    return 0.25f * (1.0f - TC[(n <= 32) ? n : (64 - n)]);
}

__global__ __launch_bounds__(BLOCK_THREADS, 2)   // VGPR cap 256, no spills
void SpectralTokenizer_36103495090536_kernel(const float* __restrict__ in,
                                             float* __restrict__ out,
                                             int nrows) {
    __shared__ float so[HALF_ROWS * OUT_PER_ROW];  // 21,120 B -> 6 blocks/CU (30 waves)

    const int tid = threadIdx.x;
    const int row_local = tid / 5;
    const int frame = tid - row_local * 5;
    const long long row = (long long)blockIdx.x * ROWS_PER_BLOCK + row_local;
    const bool active = (row < (long long)nrows);

    float ar[32], ai[32];

    if (active) {
        // Load 64 windowed samples as 16 aligned float4s, pack directly into
        // bit-reversed complex slots: a[br(n)] = (x[2n]*w/2, x[2n+1]*w/2).
        // Frame overlap replays L1 lines ~8x but R3 proved that's cheaper than
        // an LDS staging round-trip.
        const float4* src = (const float4*)(in + row * ROW_LEN + frame * 8);
#pragma unroll
        for (int i = 0; i < 16; i++) {
            float4 v = src[i];
            const int p0 = BR32[2 * i], p1 = BR32[2 * i + 1];
            ar[p0] = v.x * hann_half(4 * i + 0);
            ai[p0] = v.y * hann_half(4 * i + 1);
            ar[p1] = v.z * hann_half(4 * i + 2);
            ai[p1] = v.w * hann_half(4 * i + 3);
        }

#define BUTTERFLY(i0, i1, c, sn)                                   \
        {                                                          \
            float tr = (c) * ar[i1] + (sn) * ai[i1];               \
            float ti = (c) * ai[i1] - (sn) * ar[i1];               \
            float ur = ar[i0], ui = ai[i0];                        \
            ar[i0] = ur + tr; ai[i0] = ui + ti;                    \
            ar[i1] = ur - tr; ai[i1] = ui - ti;                    \
        }

        // Stage 1 (m=2): twiddle = 1
#pragma unroll
        for (int t = 0; t < 16; t++) BUTTERFLY(2 * t, 2 * t + 1, 1.0f, 0.0f);
        // Stage 2 (m=4): j=0 -> 1 ; j=1 -> -i
#pragma unroll
        for (int t = 0; t < 8; t++) {
            const int k = 4 * t;
            BUTTERFLY(k + 0, k + 2, 1.0f, 0.0f);
            BUTTERFLY(k + 1, k + 3, 0.0f, 1.0f);
        }
        // Stage 3 (m=8): j*4
#pragma unroll
        for (int t = 0; t < 4; t++) {
            const int k = 8 * t;
            BUTTERFLY(k + 0, k + 4, 1.0f, 0.0f);
            BUTTERFLY(k + 1, k + 5, W32C[4], W32S[4]);
            BUTTERFLY(k + 2, k + 6, 0.0f, 1.0f);
            BUTTERFLY(k + 3, k + 7, W32C[12], W32S[12]);
        }
        // Stage 4 (m=16): j*2
#pragma unroll
        for (int t = 0; t < 2; t++) {
            const int k = 16 * t;
#pragma unroll
            for (int j = 0; j < 8; j++) BUTTERFLY(k + j, k + j + 8, W32C[2 * j], W32S[2 * j]);
        }
        // Stage 5 (m=32): j
#pragma unroll
        for (int j = 0; j < 16; j++) BUTTERFLY(j, j + 16, W32C[j], W32S[j]);
#undef BUTTERFLY
    }

    // Real-FFT reconstruction (0.5 folded into window), magnitude, log1p;
    // freq-major into LDS. Bank = (l + 5k) mod 32 over the wave's 64 lanes ->
    // only the free lane/lane+32 2-way alias.
#define RECON_TO_LDS(local_row)                                            \
    {                                                                      \
        float* orow = so + (local_row) * OUT_PER_ROW + frame;              \
        _Pragma("unroll")                                                  \
        for (int k = 0; k <= 32; k++) {                                    \
            const int km = k & 31;                                         \
            const int kc = (32 - k) & 31;                                  \
            const float er = ar[km] + ar[kc];                              \
            const float ei = ai[km] - ai[kc];                              \
            const float pr = ai[km] + ai[kc];                              \
            const float pi = ar[kc] - ar[km];                              \
            const float xr = er + TC[k] * pr + TS[k] * pi;                 \
            const float xi = ei + TC[k] * pi - TS[k] * pr;                 \
            const float mag = sqrtf(xr * xr + xi * xi);                    \
            orow[k * 5] = __logf(1.0f + mag);                              \
        }                                                                  \
    }

    const long long block_base = (long long)blockIdx.x * (ROWS_PER_BLOCK * OUT_PER_ROW);
    const long long total_out = (long long)nrows * OUT_PER_ROW;

    // ---- Pass A: rows 0..31 ----
    if (active && row_local < HALF_ROWS) RECON_TO_LDS(row_local);
    __syncthreads();
    {
        nfloat4* dst = (nfloat4*)(out + block_base);
        const nfloat4* s4 = (const nfloat4*)so;
#pragma unroll 2
        for (int t = tid; t < CHUNK_F4; t += BLOCK_THREADS) {
            if (block_base + 4 * t + 3 < total_out)
                __builtin_nontemporal_store(s4[t], &dst[t]);
        }
    }
    __syncthreads();

    // ---- Pass B: rows 32..63 (ar/ai stayed live in registers) ----
    if (active && row_local >= HALF_ROWS) RECON_TO_LDS(row_local - HALF_ROWS);
    __syncthreads();
    {
        const long long chunk_base = block_base + (HALF_ROWS * OUT_PER_ROW);
        nfloat4* dst = (nfloat4*)(out + chunk_base);
        const nfloat4* s4 = (const nfloat4*)so;
#pragma unroll 2
        for (int t = tid; t < CHUNK_F4; t += BLOCK_THREADS) {
            if (chunk_base + 4 * t + 3 < total_out)
                __builtin_nontemporal_store(s4[t], &dst[t]);
        }
    }
#undef RECON_TO_LDS
}

extern "C" void kernel_launch(void* const* d_in, const int* in_sizes, int n_in,
                              void* d_out, int out_size, void* d_ws, size_t ws_size,
                              hipStream_t stream) {
    const float* in = (const float*)d_in[0];
    float* out = (float*)d_out;
    const int nrows = in_sizes[0] / ROW_LEN;                        // 262144
    const int grid = (nrows + ROWS_PER_BLOCK - 1) / ROWS_PER_BLOCK; // 4096
    hipLaunchKernelGGL(SpectralTokenizer_36103495090536_kernel,
                       dim3(grid), dim3(BLOCK_THREADS), 0, stream, in, out, nrows);
}

// Round 6
// 268.098 us; speedup vs baseline: 1.2749x; 1.2749x over previous
//
#include <hip/hip_runtime.h>
#include <math.h>

// SpectralTokenizer: 262144 rows x 100 fp32 -> per row 5 frames (hop 8, len 64),
// Hann window, rfft-64, log1p(|.|), freq-major flatten -> 165 fp32 per row.
//
// R8 (final): revert to the maximally-verified configuration (passed full
// harness incl. post-timing tripwires twice at 265.3/266.7us). Session
// findings, all counter-verified:
//  - R3: LDS input staging regressed 56->159us kernel (bank conflicts + 3
//    barriers unhidden at 3 blocks/CU). Scattered loads + L1 replay win.
//  - R6: split-transpose (21KB LDS) DROPPED occupancy 22.7->14.5% and
//    tripled kernel time — half-active barrier phases convoy.
//  - R7: nt-stores + paired recon passed pre-check but failed the
//    post-timing re-poison tripwire (absmax 2.89, timing-dependent);
//    suspect nt no-allocate write racing poison-fill L2 evictions. Reverted.
// Metric floor: 265us = 2 x ~104us harness re-poison fills (83% HBM peak,
// not controllable) + ~56us kernel (vs ~40us latency-inclusive floor; all
// structural attacks on the gap regressed).

#define ROWS_PER_BLOCK 64
#define BLOCK_THREADS (ROWS_PER_BLOCK * 5)   // 320 = 5 waves
#define ROW_LEN 100
#define OUT_PER_ROW 165                      // 33 freq * 5 frames

// cos/sin(2*pi*j/32), j=0..15  (FFT-32 twiddles, e^{-2pi i j/32} = c - i*s)
constexpr float W32C[16] = {
    1.0f, 0.980785280403230f, 0.923879532511287f, 0.831469612302545f,
    0.707106781186548f, 0.555570233019602f, 0.382683432365090f, 0.195090322016128f,
    0.0f, -0.195090322016128f, -0.382683432365090f, -0.555570233019602f,
    -0.707106781186548f, -0.831469612302545f, -0.923879532511287f, -0.980785280403230f};
constexpr float W32S[16] = {
    0.0f, 0.195090322016128f, 0.382683432365090f, 0.555570233019602f,
    0.707106781186548f, 0.831469612302545f, 0.923879532511287f, 0.980785280403230f,
    1.0f, 0.980785280403230f, 0.923879532511287f, 0.831469612302545f,
    0.707106781186548f, 0.555570233019602f, 0.382683432365090f, 0.195090322016128f};

// cos/sin(2*pi*k/64), k=0..32 (recon twiddles e^{-2pi i k/64} = TC - i*TS; also Hann table)
constexpr float TC[33] = {
    1.0f, 0.995184726672197f, 0.980785280403230f, 0.956940335732209f,
    0.923879532511287f, 0.881921264348355f, 0.831469612302545f, 0.773010453362737f,
    0.707106781186548f, 0.634393284163645f, 0.555570233019602f, 0.471396736825998f,
    0.382683432365090f, 0.290284677254462f, 0.195090322016128f, 0.098017140329561f,
    0.0f, -0.098017140329561f, -0.195090322016128f, -0.290284677254462f,
    -0.382683432365090f, -0.471396736825998f, -0.555570233019602f, -0.634393284163645f,
    -0.707106781186548f, -0.773010453362737f, -0.831469612302545f, -0.881921264348355f,
    -0.923879532511287f, -0.956940335732209f, -0.980785280403230f, -0.995184726672197f,
    -1.0f};
constexpr float TS[33] = {
    0.0f, 0.098017140329561f, 0.195090322016128f, 0.290284677254462f,
    0.382683432365090f, 0.471396736825998f, 0.555570233019602f, 0.634393284163645f,
    0.707106781186548f, 0.773010453362737f, 0.831469612302545f, 0.881921264348355f,
    0.923879532511287f, 0.956940335732209f, 0.980785280403230f, 0.995184726672197f,
    1.0f, 0.995184726672197f, 0.980785280403230f, 0.956940335732209f,
    0.923879532511287f, 0.881921264348355f, 0.831469612302545f, 0.773010453362737f,
    0.707106781186548f, 0.634393284163645f, 0.555570233019602f, 0.471396736825998f,
    0.382683432365090f, 0.290284677254462f, 0.195090322016128f, 0.098017140329561f};

// 5-bit bit reversal (involution)
constexpr int BR32[32] = {0, 16, 8, 24, 4, 20, 12, 28, 2, 18, 10, 26, 6, 22, 14, 30,
                          1, 17, 9, 25, 5, 21, 13, 29, 3, 19, 11, 27, 7, 23, 15, 31};

// periodic Hann scaled by 0.5 (the even/odd extraction factor folded in):
// w[n] = 0.25*(1 - cos(2*pi*n/64)); n compile-time -> folds to a literal
__device__ __forceinline__ constexpr float hann_half(int n) {
    return 0.25f * (1.0f - TC[(n <= 32) ? n : (64 - n)]);
}

__global__ __launch_bounds__(BLOCK_THREADS, 2)   // min 2 waves/EU -> VGPR cap 256, no spills
void SpectralTokenizer_36103495090536_kernel(const float* __restrict__ in,
                                             float* __restrict__ out,
                                             int nrows) {
    __shared__ float so[ROWS_PER_BLOCK * OUT_PER_ROW];  // 42,240 B -> 3 blocks/CU

    const int tid = threadIdx.x;
    const int row_local = tid / 5;
    const int frame = tid - row_local * 5;
    const long long row = (long long)blockIdx.x * ROWS_PER_BLOCK + row_local;
    const bool active = (row < (long long)nrows);

    float ar[32], ai[32];

    if (active) {
        // Load 64 windowed samples as 16 aligned float4s, pack directly into
        // bit-reversed complex slots: a[br(n)] = (x[2n]*w/2, x[2n+1]*w/2).
        // Frame overlap replays L1 lines ~8x but R3/R6 proved that's cheaper
        // than any LDS staging / multi-barrier restructuring.
        const float4* src = (const float4*)(in + row * ROW_LEN + frame * 8);
#pragma unroll
        for (int i = 0; i < 16; i++) {
            float4 v = src[i];
            const int p0 = BR32[2 * i], p1 = BR32[2 * i + 1];
            ar[p0] = v.x * hann_half(4 * i + 0);
            ai[p0] = v.y * hann_half(4 * i + 1);
            ar[p1] = v.z * hann_half(4 * i + 2);
            ai[p1] = v.w * hann_half(4 * i + 3);
        }

#define BUTTERFLY(i0, i1, c, sn)                                   \
        {                                                          \
            float tr = (c) * ar[i1] + (sn) * ai[i1];               \
            float ti = (c) * ai[i1] - (sn) * ar[i1];               \
            float ur = ar[i0], ui = ai[i0];                        \
            ar[i0] = ur + tr; ai[i0] = ui + ti;                    \
            ar[i1] = ur - tr; ai[i1] = ui - ti;                    \
        }

        // Stage 1 (m=2): twiddle = 1
#pragma unroll
        for (int t = 0; t < 16; t++) BUTTERFLY(2 * t, 2 * t + 1, 1.0f, 0.0f);
        // Stage 2 (m=4): j=0 -> 1 ; j=1 -> -i
#pragma unroll
        for (int t = 0; t < 8; t++) {
            const int k = 4 * t;
            BUTTERFLY(k + 0, k + 2, 1.0f, 0.0f);
            BUTTERFLY(k + 1, k + 3, 0.0f, 1.0f);
        }
        // Stage 3 (m=8): j*4
#pragma unroll
        for (int t = 0; t < 4; t++) {
            const int k = 8 * t;
            BUTTERFLY(k + 0, k + 4, 1.0f, 0.0f);
            BUTTERFLY(k + 1, k + 5, W32C[4], W32S[4]);
            BUTTERFLY(k + 2, k + 6, 0.0f, 1.0f);
            BUTTERFLY(k + 3, k + 7, W32C[12], W32S[12]);
        }
        // Stage 4 (m=16): j*2
#pragma unroll
        for (int t = 0; t < 2; t++) {
            const int k = 16 * t;
#pragma unroll
            for (int j = 0; j < 8; j++) BUTTERFLY(k + j, k + j + 8, W32C[2 * j], W32S[2 * j]);
        }
        // Stage 5 (m=32): j
#pragma unroll
        for (int j = 0; j < 16; j++) BUTTERFLY(j, j + 16, W32C[j], W32S[j]);
#undef BUTTERFLY

        // Real-FFT reconstruction (0.5 already folded into window), magnitude,
        // log1p; write freq-major into LDS. Bank = (l + 5k) mod 32 over the
        // wave's 64 lanes -> only the free lane/lane+32 2-way alias.
        float* orow = so + row_local * OUT_PER_ROW + frame;
#pragma unroll
        for (int k = 0; k <= 32; k++) {
            const int km = k & 31;
            const int kc = (32 - k) & 31;
            const float er = ar[km] + ar[kc];
            const float ei = ai[km] - ai[kc];
            const float pr = ai[km] + ai[kc];
            const float pi = ar[kc] - ar[km];
            const float xr = er + TC[k] * pr + TS[k] * pi;
            const float xi = ei + TC[k] * pi - TS[k] * pr;
            const float mag = sqrtf(xr * xr + xi * xi);
            orow[k * 5] = __logf(1.0f + mag);
        }
    }

    __syncthreads();

    // Block-contiguous coalesced store: 64 rows * 165 floats = 2640 float4s.
    const long long block_base = (long long)blockIdx.x * (ROWS_PER_BLOCK * OUT_PER_ROW);
    const long long total_out = (long long)nrows * OUT_PER_ROW;
    float4* dst = (float4*)(out + block_base);
    const float4* s4 = (const float4*)so;
#pragma unroll 2
    for (int t = tid; t < (ROWS_PER_BLOCK * OUT_PER_ROW / 4); t += BLOCK_THREADS) {
        if (block_base + 4 * t + 3 < total_out) dst[t] = s4[t];
    }
}

extern "C" void kernel_launch(void* const* d_in, const int* in_sizes, int n_in,
                              void* d_out, int out_size, void* d_ws, size_t ws_size,
                              hipStream_t stream) {
    const float* in = (const float*)d_in[0];
    float* out = (float*)d_out;
    const int nrows = in_sizes[0] / ROW_LEN;                        // 262144
    const int grid = (nrows + ROWS_PER_BLOCK - 1) / ROWS_PER_BLOCK; // 4096
    hipLaunchKernelGGL(SpectralTokenizer_36103495090536_kernel,
                       dim3(grid), dim3(BLOCK_THREADS), 0, stream, in, out, nrows);
}